// Round 4
// baseline (23.889 us; speedup 1.0000x reference)
//
#include <hip/hip_runtime.h>
#include <hip/hip_bf16.h>
#include <cstdint>
#include <cstddef>

// out[b,c] = bias[c] + sum_i x[b,i]*(W1[i,c] + sum_j W2[i,j,c]*x[b,j])
// W flat layout: W1[i,c] = W[i*10+c]; W2[i,j,c] = W[7840 + i*7840 + j*10 + c]

typedef short short8 __attribute__((ext_vector_type(8)));
typedef float f32x4 __attribute__((ext_vector_type(4)));

#define NB   128
#define DD   784
#define NC   10
#define KCH  56     // j-chunk per block (14*56 = 784)
#define NKC  14
#define IG   16     // i per block
#define NG   49
#define NBLK (NG*NKC)   // 686
#define KPAD 64         // K padded to 2 MFMA k-steps
#define LDK  72         // LDS row stride in bf16 (64 + 8 pad; 144B = odd multiple of 16B)
#define LDKU 36         // same in u32
#define PSTRIDE 704     // padded partial depth (>= 686)

__device__ __forceinline__ uint32_t f2bfbits(float f) {
  // round-to-nearest-even f32 -> bf16 (finite inputs)
  uint32_t u = __builtin_bit_cast(uint32_t, f);
  u += 0x7FFFu + ((u >> 16) & 1u);
  return u >> 16;
}

template <int ATOMIC>
__global__ __launch_bounds__(512, 4)
void bilinear_main(const float* __restrict__ x, const float* __restrict__ W,
                   const float* __restrict__ bias, float* __restrict__ P,
                   float* __restrict__ out) {
  __shared__ unsigned short ldsW[160 * LDK];  // 23,040 B
  uint32_t* lds32 = (uint32_t*)ldsW;

  const int tid  = threadIdx.x;
  const int blk  = blockIdx.x;
  const int g    = blk / NKC;
  const int kc   = blk - g * NKC;
  const int i0   = g * IG;
  const int lane = tid & 63;
  const int w    = tid >> 6;      // wave 0..7
  const int wm   = w >> 2;        // c half (tiles 5*wm .. 5*wm+4)
  const int bq2  = w & 3;         // batch quarter (32 batches)
  const int l15  = lane & 15;
  const int q    = lane >> 4;     // lane quad
  const int jbase = kc * KCH;

  // ---- zero the k-pad columns j in [56,64) for all 160 rows ----
  #pragma unroll
  for (int z = 0; z < 2; ++z) {
    const int idx = z * 512 + tid;          // 0..639 used
    if (idx < 160 * 4) {
      const int row  = idx >> 2;
      const int colu = idx & 3;
      lds32[row * LDKU + 28 + colu] = 0;
    }
  }

  // ---- stage W2 chunk -> LDS bf16 transposed; coalesced float4 loads ----
  // group gi = il*28 + k covers i=i0+il, j = jbase+2k..2k+1, c=0..9
  // (20 contiguous, 16B-aligned floats). One round: gi = tid < 448.
  if (tid < 448) {
    const int il = tid / 28;
    const int k  = tid - il * 28;
    const float* p = W + 7840 + (size_t)(i0 + il) * 7840 + (size_t)jbase * NC + k * 20;
    const float4 a0 = ((const float4*)p)[0];
    const float4 a1 = ((const float4*)p)[1];
    const float4 a2 = ((const float4*)p)[2];
    const float4 a3 = ((const float4*)p)[3];
    const float4 a4 = ((const float4*)p)[4];
    const float v[20] = {a0.x,a0.y,a0.z,a0.w, a1.x,a1.y,a1.z,a1.w,
                         a2.x,a2.y,a2.z,a2.w, a3.x,a3.y,a3.z,a3.w,
                         a4.x,a4.y,a4.z,a4.w};
    #pragma unroll
    for (int c = 0; c < 10; ++c) {
      const uint32_t lo = f2bfbits(v[c]);
      const uint32_t hi = f2bfbits(v[c + 10]);
      lds32[(c * 16 + il) * LDKU + k] = lo | (hi << 16);
    }
  }

  // ---- B operand: x-hat fragments (lane: b = bq2*32+bg*16+l15, j = jbase+ks*32+q*8+e) ----
  short8 bq[2][2];
  #pragma unroll
  for (int bg = 0; bg < 2; ++bg) {
    const int b = bq2 * 32 + bg * 16 + l15;
    const float* xrow = x + (size_t)b * DD + jbase;
    #pragma unroll
    for (int ks = 0; ks < 2; ++ks) {
      const int jloc = ks * 32 + q * 8;
      float v[8];
      if (jloc < KCH) {
        const float4 p0 = *(const float4*)(xrow + jloc);
        const float4 p1 = *(const float4*)(xrow + jloc + 4);
        v[0] = p0.x; v[1] = p0.y; v[2] = p0.z; v[3] = p0.w;
        v[4] = p1.x; v[5] = p1.y; v[6] = p1.z; v[7] = p1.w;
      } else {
        #pragma unroll
        for (int e = 0; e < 8; ++e) v[e] = 0.f;
      }
      short8 s;
      #pragma unroll
      for (int e = 0; e < 8; ++e) s[e] = (short)f2bfbits(v[e]);
      bq[bg][ks] = s;
    }
  }

  // ---- hoisted epilogue weights: x[b, i] f32 (i = i0 + q*4 + r) ----
  float xv[2][4];
  #pragma unroll
  for (int bg = 0; bg < 2; ++bg) {
    const int b = bq2 * 32 + bg * 16 + l15;
    #pragma unroll
    for (int r = 0; r < 4; ++r)
      xv[bg][r] = x[(size_t)b * DD + i0 + q * 4 + r];
  }

  __syncthreads();

  // ---- MFMA: A = W2-tile (rows: c fixed per tile, m = i-local), B = x-hat ----
  float yacc[2][5] = {};   // [bg][t]  (c = wm*5 + t static per slot)
  const int tbase = wm * 5;
  #pragma unroll
  for (int t = 0; t < 5; ++t) {
    const int tile = tbase + t;          // tile index == c
    f32x4 acc[2] = {};
    const unsigned short* arow = &ldsW[(tile * 16 + l15) * LDK + q * 8];
    #pragma unroll
    for (int ks = 0; ks < 2; ++ks) {
      const short8 a = *(const short8*)(arow + ks * 32);
      #pragma unroll
      for (int bg = 0; bg < 2; ++bg)
        acc[bg] = __builtin_amdgcn_mfma_f32_16x16x32_bf16(a, bq[bg][ks], acc[bg], 0, 0, 0);
    }
    // epilogue: y[b,c] += x[b,i] * (T[b,i,c] + W1[i,c] once at kc==0)
    #pragma unroll
    for (int r = 0; r < 4; ++r) {
      float w1 = 0.f;
      if (kc == 0) w1 = W[(i0 + q * 4 + r) * NC + tile];
      #pragma unroll
      for (int bg = 0; bg < 2; ++bg)
        yacc[bg][t] += xv[bg][r] * (acc[bg][r] + w1);
    }
  }

  // ---- reduce over lane-quads (each q holds a different i-subset), emit ----
  #pragma unroll
  for (int bg = 0; bg < 2; ++bg) {
    #pragma unroll
    for (int t = 0; t < 5; ++t) {
      float v = yacc[bg][t];
      v += __shfl_down(v, 16);
      v += __shfl_down(v, 32);
      if (q == 0) {
        const int bc = (bq2 * 32 + bg * 16 + l15) * NC + tbase + t;
        if constexpr (ATOMIC == 0) {
          P[(size_t)bc * PSTRIDE + blk] = v;
        } else {
          if (blk == 0) v += bias[tbase + t];
          atomicAdd(&out[bc], v);
        }
      }
    }
  }
}

__global__ __launch_bounds__(512)
void reduce_partials(const float* __restrict__ P, const float* __restrict__ bias,
                     float* __restrict__ out) {
  const int w  = threadIdx.x >> 6;            // wave 0..7
  const int l  = threadIdx.x & 63;
  const int bc = blockIdx.x * 8 + w;          // 0..1279
  float s = 0.f;
  #pragma unroll
  for (int it = 0; it < 11; ++it) {
    const int k = it * 64 + l;
    if (k < NBLK) s += P[(size_t)bc * PSTRIDE + k];
  }
  #pragma unroll
  for (int off = 32; off; off >>= 1) s += __shfl_down(s, off);
  if (l == 0) out[bc] = s + bias[bc % NC];
}

extern "C" void kernel_launch(void* const* d_in, const int* in_sizes, int n_in,
                              void* d_out, int out_size, void* d_ws, size_t ws_size,
                              hipStream_t stream) {
  const float* x    = (const float*)d_in[0];
  const float* W    = (const float*)d_in[1];
  const float* bias = (const float*)d_in[2];
  float* out = (float*)d_out;
  float* P   = (float*)d_ws;

  const size_t need = (size_t)NB * NC * PSTRIDE * sizeof(float);  // ~3.6 MB
  if (ws_size >= need) {
    bilinear_main<0><<<NBLK, 512, 0, stream>>>(x, W, bias, P, out);
    reduce_partials<<<160, 512, 0, stream>>>(P, bias, out);
  } else {
    hipMemsetAsync(d_out, 0, (size_t)NB * NC * sizeof(float), stream);
    bilinear_main<1><<<NBLK, 512, 0, stream>>>(x, W, bias, P, out);
  }
}